// Round 3
// baseline (7157.890 us; speedup 1.0000x reference)
//
#include <hip/hip_runtime.h>
#include <math.h>

constexpr int Lc   = 2048;  // L_IN
constexpr int DECc = 64;    // DEC_LEN
constexpr int Hc   = 128;   // H
constexpr int Gc   = 512;   // 4*H
constexpr int EMBc = 16;    // EMB
constexpr int INc  = 18;    // IN_SIZE
constexpr int NBc  = 4;     // batches per block
constexpr int NTc  = 512;   // threads per block

__device__ __forceinline__ float fast_sigmoid(float x) {
    return 1.0f / (1.0f + exp2f(-1.44269504f * x));
}
__device__ __forceinline__ float fast_tanh(float x) {
    return 2.0f / (1.0f + exp2f(-2.88539008f * x)) - 1.0f;
}
__device__ __forceinline__ float fast_softplus(float x) {
    return 0.69314718f * log2f(1.0f + exp2f(1.44269504f * x));
}

__global__ __launch_bounds__(NTc, 2) void rnnar_kernel(
    const int*   __restrict__ cat_in,  const float* __restrict__ cont_in,
    const float* __restrict__ X_in,    const int*   __restrict__ cat_out,
    const float* __restrict__ cont_out,const float* __restrict__ emb_table,
    const float* __restrict__ cont_w,
    const float* __restrict__ Wih_e, const float* __restrict__ Whh_e, const float* __restrict__ b_e,
    const float* __restrict__ Wih_d, const float* __restrict__ Whh_d, const float* __restrict__ b_d,
    const float* __restrict__ Wm, const float* __restrict__ bm,
    const float* __restrict__ Ws, const float* __restrict__ bs,
    const float* __restrict__ Wv, const float* __restrict__ bv,
    float* __restrict__ out)
{
    __shared__ __align__(16) float h_lds[Hc * NBc];   // [k][b] float4 rows
    __shared__ __align__(16) float x_lds[INc * NBc];  // [k][b]
    __shared__ float g_lds[NBc * Gc];                 // [b][gate]
    __shared__ float mu_lds[NBc];

    const int tid = threadIdx.x;
    const int b0  = blockIdx.x * NBc;
    const float w00 = cont_w[0];

    // per-thread weight registers: row `tid` of Whh / Wih
    float w[Hc];
    float wi[INc];
    float bias;
    {
        const float* wr = Whh_e + tid * Hc;
        #pragma unroll
        for (int k = 0; k < Hc; ++k) w[k] = wr[k];
        const float* wir = Wih_e + tid * INc;
        #pragma unroll
        for (int k = 0; k < INc; ++k) wi[k] = wir[k];
        bias = b_e[tid];
    }

    // phase-2 role: this thread owns cell (m, pb)
    const int m  = tid & (Hc - 1);
    const int pb = tid >> 7;
    float c_reg = 0.0f;

    // init h(0)=0 and x(0)
    h_lds[tid] = 0.0f;  // 512 == Hc*NBc
    if (tid < INc * NBc) {
        const int k = tid >> 2, b = tid & 3, gb = b0 + b;
        float v;
        if (k < EMBc)       v = emb_table[cat_in[gb * Lc] * EMBc + k];
        else if (k == EMBc) v = cont_in[gb * Lc] * w00;
        else                v = X_in[gb * Lc];
        x_lds[tid] = v;
    }
    __syncthreads();

    // ===================== encoder: 2048 sequential steps =====================
    for (int t = 0; t < Lc; ++t) {
        // prefetch x(t+1) into registers (overlaps with phase-1 compute)
        float xn = 0.0f;
        const bool pf = (tid < INc * NBc) && (t + 1 < Lc);
        if (pf) {
            const int k = tid >> 2, b = tid & 3, gb = b0 + b;
            if (k < EMBc)       xn = emb_table[cat_in[gb * Lc + t + 1] * EMBc + k];
            else if (k == EMBc) xn = cont_in[gb * Lc + t + 1] * w00;
            else                xn = X_in[gb * Lc + t + 1];
        }

        // phase 1: gate row `tid` for 4 batches; LDS reads are all-lane broadcasts
        float ax = bias, ay = bias, az = bias, aw = bias;
        #pragma unroll
        for (int k = 0; k < INc; ++k) {
            const float4 xv = *(const float4*)(x_lds + 4 * k);
            ax += wi[k] * xv.x; ay += wi[k] * xv.y; az += wi[k] * xv.z; aw += wi[k] * xv.w;
        }
        #pragma unroll
        for (int k = 0; k < Hc; ++k) {
            const float4 hv = *(const float4*)(h_lds + 4 * k);
            ax += w[k] * hv.x; ay += w[k] * hv.y; az += w[k] * hv.z; aw += w[k] * hv.w;
        }
        g_lds[0 * Gc + tid] = ax;
        g_lds[1 * Gc + tid] = ay;
        g_lds[2 * Gc + tid] = az;
        g_lds[3 * Gc + tid] = aw;
        __syncthreads();

        // phase 2: LSTM cell update for (m, pb)
        {
            const float gi = g_lds[pb * Gc + m];
            const float gf = g_lds[pb * Gc + m + Hc];
            const float gg = g_lds[pb * Gc + m + 2 * Hc];
            const float go = g_lds[pb * Gc + m + 3 * Hc];
            const float cn = fast_sigmoid(gf) * c_reg + fast_sigmoid(gi) * fast_tanh(gg);
            c_reg = cn;
            h_lds[m * 4 + pb] = fast_sigmoid(go) * fast_tanh(cn);
        }
        if (pf) x_lds[tid] = xn;
        __syncthreads();
    }

    // ===================== decoder =====================
    {
        const float* wr = Whh_d + tid * Hc;
        #pragma unroll
        for (int k = 0; k < Hc; ++k) w[k] = wr[k];
        const float* wir = Wih_d + tid * INc;
        #pragma unroll
        for (int k = 0; k < INc; ++k) wi[k] = wir[k];
        bias = b_d[tid];
    }
    // initial decoder x: [feats_in_embed[:, -1] (17), X_in[:, -1] (1)]
    if (tid < INc * NBc) {
        const int k = tid >> 2, b = tid & 3, gb = b0 + b;
        float v;
        if (k < EMBc)       v = emb_table[cat_in[gb * Lc + Lc - 1] * EMBc + k];
        else if (k == EMBc) v = cont_in[gb * Lc + Lc - 1] * w00;
        else                v = X_in[gb * Lc + Lc - 1];
        x_lds[tid] = v;
    }
    __syncthreads();

    const float bm0 = bm[0];
    const float bs0 = bs[0];

    for (int t = 0; t < DECc; ++t) {
        // phase 1
        float ax = bias, ay = bias, az = bias, aw = bias;
        #pragma unroll
        for (int k = 0; k < INc; ++k) {
            const float4 xv = *(const float4*)(x_lds + 4 * k);
            ax += wi[k] * xv.x; ay += wi[k] * xv.y; az += wi[k] * xv.z; aw += wi[k] * xv.w;
        }
        #pragma unroll
        for (int k = 0; k < Hc; ++k) {
            const float4 hv = *(const float4*)(h_lds + 4 * k);
            ax += w[k] * hv.x; ay += w[k] * hv.y; az += w[k] * hv.z; aw += w[k] * hv.w;
        }
        g_lds[0 * Gc + tid] = ax;
        g_lds[1 * Gc + tid] = ay;
        g_lds[2 * Gc + tid] = az;
        g_lds[3 * Gc + tid] = aw;
        __syncthreads();

        // phase 2
        {
            const float gi = g_lds[pb * Gc + m];
            const float gf = g_lds[pb * Gc + m + Hc];
            const float gg = g_lds[pb * Gc + m + 2 * Hc];
            const float go = g_lds[pb * Gc + m + 3 * Hc];
            const float cn = fast_sigmoid(gf) * c_reg + fast_sigmoid(gi) * fast_tanh(gg);
            c_reg = cn;
            h_lds[m * 4 + pb] = fast_sigmoid(go) * fast_tanh(cn);
        }
        __syncthreads();  // h ready for heads

        // phase 3: output heads (mu, std, v[0..3]) per batch
        if (tid < NBc * 8) {
            const int b = tid >> 3, o = tid & 7;
            if (o < 6) {
                const float* wv = (o == 0) ? Wm : (o == 1) ? Ws : (Wv + (o - 2) * Hc);
                float s = 0.0f;
                #pragma unroll 4
                for (int k = 0; k < Hc; ++k) s += wv[k] * h_lds[k * 4 + b];
                const int gb = b0 + b;
                if (o == 0) {
                    const float mu = s + bm0;
                    out[gb * DECc + t] = mu;
                    mu_lds[b] = mu;
                } else if (o == 1) {
                    out[65536 + gb * DECc + t] = fast_softplus(s + bs0);
                } else {
                    out[131072 + (gb * DECc + t) * 4 + (o - 2)] = s + bv[o - 2];
                }
            }
        }
        // load next feats (cat_out/cont_out at step t feed step t+1)
        float xn = 0.0f;
        if (tid < INc * NBc) {
            const int k = tid >> 2, b = tid & 3, gb = b0 + b;
            if (k < EMBc)       xn = emb_table[cat_out[gb * DECc + t] * EMBc + k];
            else if (k == EMBc) xn = cont_out[gb * DECc + t] * w00;
        }
        __syncthreads();  // mu_lds written; phase-1/head reads of x,h complete
        if (tid < INc * NBc) {
            const int k = tid >> 2, b = tid & 3;
            x_lds[tid] = (k == INc - 1) ? mu_lds[b] : xn;
        }
        __syncthreads();
    }
}

extern "C" void kernel_launch(void* const* d_in, const int* in_sizes, int n_in,
                              void* d_out, int out_size, void* d_ws, size_t ws_size,
                              hipStream_t stream) {
    rnnar_kernel<<<256, NTc, 0, stream>>>(
        (const int*)d_in[0],   (const float*)d_in[1],  (const float*)d_in[2],
        (const int*)d_in[3],   (const float*)d_in[4],  (const float*)d_in[5],
        (const float*)d_in[6],
        (const float*)d_in[7], (const float*)d_in[8],  (const float*)d_in[9],
        (const float*)d_in[10],(const float*)d_in[11], (const float*)d_in[12],
        (const float*)d_in[13],(const float*)d_in[14],
        (const float*)d_in[15],(const float*)d_in[16],
        (const float*)d_in[17],(const float*)d_in[18],
        (float*)d_out);
}

// Round 4
// 4267.788 us; speedup vs baseline: 1.6772x; 1.6772x over previous
//
#include <hip/hip_runtime.h>
#include <math.h>

typedef _Float16 half8 __attribute__((ext_vector_type(8)));
typedef float float4v __attribute__((ext_vector_type(4)));

constexpr int Lc   = 2048;  // L_IN
constexpr int DECc = 64;    // DEC_LEN
constexpr int Hc   = 128;   // H
constexpr int EMBc = 16;    // EMB
constexpr int INc  = 18;    // IN_SIZE
constexpr int NBc  = 4;     // batches per block
constexpr int NTc  = 512;   // threads per block (8 waves)
constexpr int KT   = 5;     // k-tiles of 32 (z padded to 160)

__device__ __forceinline__ float sigm(float x) {
    return 1.0f / (1.0f + exp2f(-1.44269504f * x));
}
__device__ __forceinline__ float tanh_(float x) {
    return 2.0f / (1.0f + exp2f(-2.88539008f * x)) - 1.0f;
}
__device__ __forceinline__ float softplus_(float x) {
    return 0.69314718f * log2f(1.0f + exp2f(1.44269504f * x));
}

// z LDS layout = B-fragment order for mfma_f32_16x16x32_f16:
// frag kt: lane l holds halves [l*8 .. l*8+8) = B[k = kt*32 + (l>>4)*8 + j][n = l&15]
// slot of (k, b): halves index
__device__ __forceinline__ int zslot(int k, int b) {
    return (k >> 5) * 512 + (b + 16 * ((k & 31) >> 3)) * 8 + (k & 7);
}

__global__ __launch_bounds__(NTc, 1) void rnnar_kernel(
    const int*   __restrict__ cat_in,  const float* __restrict__ cont_in,
    const float* __restrict__ X_in,    const int*   __restrict__ cat_out,
    const float* __restrict__ cont_out,const float* __restrict__ emb_table,
    const float* __restrict__ cont_w,
    const float* __restrict__ Wih_e, const float* __restrict__ Whh_e, const float* __restrict__ b_e,
    const float* __restrict__ Wih_d, const float* __restrict__ Whh_d, const float* __restrict__ b_d,
    const float* __restrict__ Wm, const float* __restrict__ bm,
    const float* __restrict__ Ws, const float* __restrict__ bs,
    const float* __restrict__ Wv, const float* __restrict__ bv,
    float* __restrict__ out)
{
    __shared__ _Float16 z_lds[KT * 512];      // 5 B-frags, 1KB each
    __shared__ float    h32_lds[NBc * 132];   // fp32 h for decoder heads

    const int tid  = threadIdx.x;
    const int lane = tid & 63;
    const int wv_id= tid >> 6;        // wave 0..7
    const int quad = lane >> 4;       // 0..3
    const int col  = lane & 15;       // A-row within tile / C-col (=batch)
    const int b0   = blockIdx.x * NBc;
    const float w00 = cont_w[0];

    // x-writer role (tid < 72)
    const int xk = tid >> 2, xb = tid & 3, xgb = b0 + xb;

    // zero z (padding + unused cols must stay 0 forever)
    {
        int* z32 = (int*)z_lds;
        #pragma unroll
        for (int i = tid; i < KT * 256; i += NTc) z32[i] = 0;
    }

    // ---- A-fragments: wave wv_id owns row-tiles {wv_id + 8i} = gate i rows 128i+16*wv_id.. ----
    // A layout: lane holds A[m = lane&15][k = quad*8 + j], j in [0,8)
    half8 Af[4][KT];
    float bias_[4][4];
    const int cell_base = 16 * wv_id + quad * 4;   // cells owned: cell_base + r

    #define LOAD_AB(WIH, WHH, BB)                                              \
    {                                                                          \
        _Pragma("unroll")                                                      \
        for (int i = 0; i < 4; ++i) {                                          \
            const int row = 128 * i + 16 * wv_id + col;                        \
            _Pragma("unroll")                                                  \
            for (int kt = 0; kt < KT; ++kt) {                                  \
                half8 f;                                                       \
                _Pragma("unroll")                                              \
                for (int j = 0; j < 8; ++j) {                                  \
                    const int k = 32 * kt + quad * 8 + j;                      \
                    float v = 0.0f;                                            \
                    if (k < INc)            v = WIH[row * INc + k];            \
                    else if (k < INc + Hc)  v = WHH[row * Hc + (k - INc)];     \
                    f[j] = (_Float16)v;                                        \
                }                                                              \
                Af[i][kt] = f;                                                 \
            }                                                                  \
            _Pragma("unroll")                                                  \
            for (int r = 0; r < 4; ++r)                                        \
                bias_[i][r] = BB[128 * i + cell_base + r];                     \
        }                                                                      \
    }

    LOAD_AB(Wih_e, Whh_e, b_e);

    __syncthreads();   // z zero-init visible

    // initial x(0): z[0..17]
    if (tid < INc * NBc) {
        float v;
        if (xk < EMBc)       v = emb_table[cat_in[xgb * Lc] * EMBc + xk];
        else if (xk == EMBc) v = cont_in[xgb * Lc] * w00;
        else                 v = X_in[xgb * Lc];
        z_lds[zslot(xk, xb)] = (_Float16)v;
    }
    __syncthreads();

    float c4[4] = {0.f, 0.f, 0.f, 0.f};

    // ===================== encoder =====================
    for (int t = 0; t < Lc; ++t) {
        // B frags (read phase)
        half8 bf[KT];
        #pragma unroll
        for (int kt = 0; kt < KT; ++kt)
            bf[kt] = *(const half8*)(z_lds + kt * 512 + lane * 8);

        // prefetch x(t+1)
        float xn = 0.0f;
        const bool pf = (tid < INc * NBc) && (t + 1 < Lc);
        if (pf) {
            if (xk < EMBc)       xn = emb_table[cat_in[xgb * Lc + t + 1] * EMBc + xk];
            else if (xk == EMBc) xn = cont_in[xgb * Lc + t + 1] * w00;
            else                 xn = X_in[xgb * Lc + t + 1];
        }

        // MFMA: gates for 4 gate-tiles of this wave's cells
        float4v acc[4];
        #pragma unroll
        for (int i = 0; i < 4; ++i) {
            float4v a = {0.f, 0.f, 0.f, 0.f};
            #pragma unroll
            for (int kt = 0; kt < KT; ++kt)
                a = __builtin_amdgcn_mfma_f32_16x16x32_f16(Af[i][kt], bf[kt], a, 0, 0, 0);
            acc[i] = a;
        }

        // in-register LSTM cell update (C layout: col=lane&15=batch, row=quad*4+r=cell idx)
        _Float16 hh[4];
        #pragma unroll
        for (int r = 0; r < 4; ++r) {
            const float gi = acc[0][r] + bias_[0][r];
            const float gf = acc[1][r] + bias_[1][r];
            const float gg = acc[2][r] + bias_[2][r];
            const float go = acc[3][r] + bias_[3][r];
            const float cn = sigm(gf) * c4[r] + sigm(gi) * tanh_(gg);
            c4[r] = cn;
            hh[r] = (_Float16)(sigm(go) * tanh_(cn));
        }

        __syncthreads();   // all B-frag reads done

        if (col < NBc) {
            #pragma unroll
            for (int r = 0; r < 4; ++r)
                z_lds[zslot(INc + cell_base + r, col)] = hh[r];
        }
        if (pf) z_lds[zslot(xk, xb)] = (_Float16)xn;

        __syncthreads();   // writes visible for next step
    }

    // ===================== decoder =====================
    LOAD_AB(Wih_d, Whh_d, b_d);

    // decoder x init: [feats_in_embed[:, -1], X_in[:, -1]]  (h part already = h_enc)
    if (tid < INc * NBc) {
        float v;
        if (xk < EMBc)       v = emb_table[cat_in[xgb * Lc + Lc - 1] * EMBc + xk];
        else if (xk == EMBc) v = cont_in[xgb * Lc + Lc - 1] * w00;
        else                 v = X_in[xgb * Lc + Lc - 1];
        z_lds[zslot(xk, xb)] = (_Float16)v;
    }
    __syncthreads();

    const float bm0 = bm[0], bs0 = bs[0];

    for (int t = 0; t < DECc; ++t) {
        half8 bf[KT];
        #pragma unroll
        for (int kt = 0; kt < KT; ++kt)
            bf[kt] = *(const half8*)(z_lds + kt * 512 + lane * 8);

        // prefetch feats_out[:, t] -> x for step t+1 (k < 17 only; k=17 is mu)
        float xn = 0.0f;
        const bool pf = (tid < INc * NBc) && (xk < INc - 1);
        if (pf) {
            if (xk < EMBc) xn = emb_table[cat_out[xgb * DECc + t] * EMBc + xk];
            else           xn = cont_out[xgb * DECc + t] * w00;
        }

        float4v acc[4];
        #pragma unroll
        for (int i = 0; i < 4; ++i) {
            float4v a = {0.f, 0.f, 0.f, 0.f};
            #pragma unroll
            for (int kt = 0; kt < KT; ++kt)
                a = __builtin_amdgcn_mfma_f32_16x16x32_f16(Af[i][kt], bf[kt], a, 0, 0, 0);
            acc[i] = a;
        }

        _Float16 hh[4];
        float h32v[4];
        #pragma unroll
        for (int r = 0; r < 4; ++r) {
            const float gi = acc[0][r] + bias_[0][r];
            const float gf = acc[1][r] + bias_[1][r];
            const float gg = acc[2][r] + bias_[2][r];
            const float go = acc[3][r] + bias_[3][r];
            const float cn = sigm(gf) * c4[r] + sigm(gi) * tanh_(gg);
            c4[r] = cn;
            const float hv = sigm(go) * tanh_(cn);
            h32v[r] = hv;
            hh[r] = (_Float16)hv;
        }

        __syncthreads();   // reads done

        if (col < NBc) {
            #pragma unroll
            for (int r = 0; r < 4; ++r) {
                z_lds[zslot(INc + cell_base + r, col)] = hh[r];
                h32_lds[col * 132 + cell_base + r]     = h32v[r];
            }
        }
        if (pf) z_lds[zslot(xk, xb)] = (_Float16)xn;

        __syncthreads();   // h32 + z visible

        // heads: mu, std, v[0..3] per batch
        if (tid < NBc * 8) {
            const int b = tid >> 3, o = tid & 7;
            if (o < 6) {
                const float* wvp = (o == 0) ? Wm : (o == 1) ? Ws : (Wv + (o - 2) * Hc);
                float s = 0.0f;
                #pragma unroll 8
                for (int k = 0; k < Hc; ++k) s += wvp[k] * h32_lds[b * 132 + k];
                const int gb = b0 + b;
                if (o == 0) {
                    const float mu = s + bm0;
                    out[gb * DECc + t] = mu;
                    z_lds[zslot(INc - 1, b)] = (_Float16)mu;   // feedback
                } else if (o == 1) {
                    out[65536 + gb * DECc + t] = softplus_(s + bs0);
                } else {
                    out[131072 + (gb * DECc + t) * 4 + (o - 2)] = s + bv[o - 2];
                }
            }
        }
        __syncthreads();   // mu written before next read phase
    }
    #undef LOAD_AB
}

extern "C" void kernel_launch(void* const* d_in, const int* in_sizes, int n_in,
                              void* d_out, int out_size, void* d_ws, size_t ws_size,
                              hipStream_t stream) {
    rnnar_kernel<<<256, NTc, 0, stream>>>(
        (const int*)d_in[0],   (const float*)d_in[1],  (const float*)d_in[2],
        (const int*)d_in[3],   (const float*)d_in[4],  (const float*)d_in[5],
        (const float*)d_in[6],
        (const float*)d_in[7], (const float*)d_in[8],  (const float*)d_in[9],
        (const float*)d_in[10],(const float*)d_in[11], (const float*)d_in[12],
        (const float*)d_in[13],(const float*)d_in[14],
        (const float*)d_in[15],(const float*)d_in[16],
        (const float*)d_in[17],(const float*)d_in[18],
        (float*)d_out);
}

// Round 5
// 2227.565 us; speedup vs baseline: 3.2133x; 1.9159x over previous
//
#include <hip/hip_runtime.h>
#include <math.h>

typedef _Float16 half8 __attribute__((ext_vector_type(8)));
typedef float float4v __attribute__((ext_vector_type(4)));

constexpr int Lc   = 2048;  // L_IN
constexpr int DECc = 64;    // DEC_LEN
constexpr int Hc   = 128;   // H
constexpr int EMBc = 16;    // EMB
constexpr int INc  = 18;    // IN_SIZE
constexpr int NBc  = 4;     // batches per block
constexpr int NTc  = 512;   // threads per block (8 waves)
constexpr int KT   = 5;     // k-tiles of 32 (z padded to 160)
constexpr int GS   = 520;   // g_lds per-batch stride (512 + 8 pad: b128 writes max 2-way = free)

__device__ __forceinline__ float sigm(float x) {
    return 1.0f / (1.0f + exp2f(-1.44269504f * x));
}
__device__ __forceinline__ float tanh_(float x) {
    return 2.0f / (1.0f + exp2f(-2.88539008f * x)) - 1.0f;
}
__device__ __forceinline__ float softplus_(float x) {
    return 0.69314718f * log2f(1.0f + exp2f(1.44269504f * x));
}

// z LDS layout = B-fragment order for mfma_f32_16x16x32_f16 (verified R4):
// frag kt: lane l holds halves [l*8..l*8+8) = B[k = kt*32 + (l>>4)*8 + j][n = l&15]
__device__ __forceinline__ int zslot(int k, int b) {
    return (k >> 5) * 512 + (b + 16 * ((k & 31) >> 3)) * 8 + (k & 7);
}

__global__ __launch_bounds__(NTc, 1) void rnnar_kernel(
    const int*   __restrict__ cat_in,  const float* __restrict__ cont_in,
    const float* __restrict__ X_in,    const int*   __restrict__ cat_out,
    const float* __restrict__ cont_out,const float* __restrict__ emb_table,
    const float* __restrict__ cont_w,
    const float* __restrict__ Wih_e, const float* __restrict__ Whh_e, const float* __restrict__ b_e,
    const float* __restrict__ Wih_d, const float* __restrict__ Whh_d, const float* __restrict__ b_d,
    const float* __restrict__ Wm, const float* __restrict__ bm,
    const float* __restrict__ Ws, const float* __restrict__ bs,
    const float* __restrict__ Wv, const float* __restrict__ bv,
    float* __restrict__ out)
{
    __shared__ _Float16      z_lds[KT * 512];     // 5 KB   (B-frags)
    __shared__ float         g_lds[NBc * GS];     // 8.3 KB (gate pre-activations incl bias)
    __shared__ float         h32_lds[NBc * 132];  // 2.1 KB (fp32 h for decoder heads)
    __shared__ unsigned char catb[NBc * 2048];    // 8 KB   (cat_in indices, CARD=200<256)
    __shared__ unsigned char catob[NBc * DECc];   // 256 B

    const int tid  = threadIdx.x;
    const int lane = tid & 63;
    const int wv   = tid >> 6;        // wave 0..7
    const int quad = lane >> 4;       // 0..3
    const int col  = lane & 15;       // C-col (= batch)
    const int b0   = blockIdx.x * NBc;
    const float w00 = cont_w[0];

    // x-writer role (tid < 72)
    const int xk = tid >> 2, xb = tid & 3, xgb = b0 + xb;
    // phase-2 role: this thread owns cell m of batch pb
    const int m = tid & (Hc - 1), pb = tid >> 7;

    // zero z (padding + unused cols must stay 0 forever)
    {
        int* z32 = (int*)z_lds;
        for (int i = tid; i < KT * 256; i += NTc) z32[i] = 0;
    }
    // preload categorical indices into LDS (coalesced global reads)
    for (int i = tid; i < NBc * 2048; i += NTc) {
        const int b = i >> 11, t = i & 2047;
        catb[i] = (unsigned char)cat_in[(b0 + b) * Lc + t];
    }
    for (int i = tid; i < NBc * DECc; i += NTc) {
        const int b = i >> 6, t = i & 63;
        catob[i] = (unsigned char)cat_out[(b0 + b) * DECc + t];
    }

    // ---- A-fragments: wave wv owns row-tiles {wv + 8i} = gate i, cells 16wv..16wv+15 ----
    half8 Af[4][KT];
    float4v bias4[4];                      // acc init = bias (C rows quad*4+r, same all cols)
    const int cell_base = 16 * wv + quad * 4;

    #define LOAD_AB(WIH, WHH, BB)                                              \
    {                                                                          \
        _Pragma("unroll")                                                      \
        for (int i = 0; i < 4; ++i) {                                          \
            const int row = 128 * i + 16 * wv + col;                           \
            _Pragma("unroll")                                                  \
            for (int kt = 0; kt < KT; ++kt) {                                  \
                half8 f;                                                       \
                _Pragma("unroll")                                              \
                for (int j = 0; j < 8; ++j) {                                  \
                    const int k = 32 * kt + quad * 8 + j;                      \
                    float v = 0.0f;                                            \
                    if (k < INc)            v = WIH[row * INc + k];            \
                    else if (k < INc + Hc)  v = WHH[row * Hc + (k - INc)];     \
                    f[j] = (_Float16)v;                                        \
                }                                                              \
                Af[i][kt] = f;                                                 \
            }                                                                  \
            float4v bb;                                                        \
            _Pragma("unroll")                                                  \
            for (int r = 0; r < 4; ++r) bb[r] = BB[128 * i + cell_base + r];   \
            bias4[i] = bb;                                                     \
        }                                                                      \
    }

    LOAD_AB(Wih_e, Whh_e, b_e);

    __syncthreads();   // z zero + catb visible

    // x(0) stored; xreg = x(1) (2-step pipeline reg)
    float xreg = 0.f;
    if (tid < INc * NBc) {
        float v0, v1;
        if (xk < EMBc) {
            v0 = emb_table[(int)catb[xb * 2048 + 0] * EMBc + xk];
            v1 = emb_table[(int)catb[xb * 2048 + 1] * EMBc + xk];
        } else if (xk == EMBc) {
            v0 = cont_in[xgb * Lc + 0] * w00;
            v1 = cont_in[xgb * Lc + 1] * w00;
        } else {
            v0 = X_in[xgb * Lc + 0];
            v1 = X_in[xgb * Lc + 1];
        }
        z_lds[zslot(xk, xb)] = (_Float16)v0;
        xreg = v1;
    }
    __syncthreads();

    float c_reg = 0.f;
    const _Float16* zp = z_lds + lane * 8;

    // ===================== encoder =====================
    for (int t = 0; t < Lc; ++t) {
        // issue x(t+2) loads (2-step window covers HBM latency)
        float xf = 0.f;
        if (tid < INc * NBc) {
            const int t2 = (t + 2 < Lc) ? t + 2 : Lc - 1;
            if (xk < EMBc)       xf = emb_table[(int)catb[xb * 2048 + t2] * EMBc + xk];
            else if (xk == EMBc) xf = cont_in[xgb * Lc + t2] * w00;
            else                 xf = X_in[xgb * Lc + t2];
        }

        // phase 1: MFMA gates
        half8 bf[KT];
        #pragma unroll
        for (int kt = 0; kt < KT; ++kt) bf[kt] = *(const half8*)(zp + kt * 512);
        float4v acc[4];
        #pragma unroll
        for (int i = 0; i < 4; ++i) {
            float4v a = bias4[i];
            #pragma unroll
            for (int kt = 0; kt < KT; ++kt)
                a = __builtin_amdgcn_mfma_f32_16x16x32_f16(Af[i][kt], bf[kt], a, 0, 0, 0);
            acc[i] = a;
        }
        if (col < NBc) {
            #pragma unroll
            for (int i = 0; i < 4; ++i)
                *(float4v*)(g_lds + col * GS + i * 128 + cell_base) = acc[i];
        }
        __syncthreads();

        // phase 2: one cell-update per thread (cell m, batch pb)
        {
            const float gi = g_lds[pb * GS + m];
            const float gf = g_lds[pb * GS + 128 + m];
            const float gg = g_lds[pb * GS + 256 + m];
            const float go = g_lds[pb * GS + 384 + m];
            const float cn = sigm(gf) * c_reg + sigm(gi) * tanh_(gg);
            c_reg = cn;
            z_lds[zslot(INc + m, pb)] = (_Float16)(sigm(go) * tanh_(cn));
        }
        if (tid < INc * NBc) z_lds[zslot(xk, xb)] = (_Float16)xreg;  // x(t+1)
        xreg = xf;
        __syncthreads();
    }

    // ===================== decoder =====================
    LOAD_AB(Wih_d, Whh_d, b_d);

    if (tid < INc * NBc) {
        float v;
        if (xk < EMBc)       v = emb_table[(int)catb[xb * 2048 + (Lc - 1)] * EMBc + xk];
        else if (xk == EMBc) v = cont_in[xgb * Lc + Lc - 1] * w00;
        else                 v = X_in[xgb * Lc + Lc - 1];
        z_lds[zslot(xk, xb)] = (_Float16)v;
    }
    __syncthreads();

    const float bm0 = bm[0], bs0 = bs[0];

    for (int t = 0; t < DECc; ++t) {
        // prefetch feats_out[:, t] -> x(t+1) (k<17; k=17 slot is mu, written by heads)
        float xf = 0.f;
        if (tid < INc * NBc && xk < INc - 1) {
            if (xk < EMBc) xf = emb_table[(int)catob[xb * DECc + t] * EMBc + xk];
            else           xf = cont_out[xgb * DECc + t] * w00;
        }

        half8 bf[KT];
        #pragma unroll
        for (int kt = 0; kt < KT; ++kt) bf[kt] = *(const half8*)(zp + kt * 512);
        float4v acc[4];
        #pragma unroll
        for (int i = 0; i < 4; ++i) {
            float4v a = bias4[i];
            #pragma unroll
            for (int kt = 0; kt < KT; ++kt)
                a = __builtin_amdgcn_mfma_f32_16x16x32_f16(Af[i][kt], bf[kt], a, 0, 0, 0);
            acc[i] = a;
        }
        if (col < NBc) {
            #pragma unroll
            for (int i = 0; i < 4; ++i)
                *(float4v*)(g_lds + col * GS + i * 128 + cell_base) = acc[i];
        }
        __syncthreads();

        // phase 2
        {
            const float gi = g_lds[pb * GS + m];
            const float gf = g_lds[pb * GS + 128 + m];
            const float gg = g_lds[pb * GS + 256 + m];
            const float go = g_lds[pb * GS + 384 + m];
            const float cn = sigm(gf) * c_reg + sigm(gi) * tanh_(gg);
            c_reg = cn;
            const float hv = sigm(go) * tanh_(cn);
            z_lds[zslot(INc + m, pb)] = (_Float16)hv;
            h32_lds[pb * 132 + m] = hv;
        }
        if (tid < INc * NBc && xk < INc - 1) z_lds[zslot(xk, xb)] = (_Float16)xf;
        __syncthreads();

        // phase 3: heads (mu, std, v[0..3]) per batch
        if (tid < NBc * 8) {
            const int b = tid >> 3, o = tid & 7;
            if (o < 6) {
                const float* wvp = (o == 0) ? Wm : (o == 1) ? Ws : (Wv + (o - 2) * Hc);
                float s = 0.0f;
                #pragma unroll 8
                for (int k = 0; k < Hc; ++k) s += wvp[k] * h32_lds[b * 132 + k];
                const int gb = b0 + b;
                if (o == 0) {
                    const float mu = s + bm0;
                    out[gb * DECc + t] = mu;
                    z_lds[zslot(INc - 1, b)] = (_Float16)mu;   // mu feedback
                } else if (o == 1) {
                    out[65536 + gb * DECc + t] = softplus_(s + bs0);
                } else {
                    out[131072 + (gb * DECc + t) * 4 + (o - 2)] = s + bv[o - 2];
                }
            }
        }
        __syncthreads();
    }
    #undef LOAD_AB
}

extern "C" void kernel_launch(void* const* d_in, const int* in_sizes, int n_in,
                              void* d_out, int out_size, void* d_ws, size_t ws_size,
                              hipStream_t stream) {
    rnnar_kernel<<<256, NTc, 0, stream>>>(
        (const int*)d_in[0],   (const float*)d_in[1],  (const float*)d_in[2],
        (const int*)d_in[3],   (const float*)d_in[4],  (const float*)d_in[5],
        (const float*)d_in[6],
        (const float*)d_in[7], (const float*)d_in[8],  (const float*)d_in[9],
        (const float*)d_in[10],(const float*)d_in[11], (const float*)d_in[12],
        (const float*)d_in[13],(const float*)d_in[14],
        (const float*)d_in[15],(const float*)d_in[16],
        (const float*)d_in[17],(const float*)d_in[18],
        (float*)d_out);
}